// Round 11
// baseline (145.190 us; speedup 1.0000x reference)
//
#include <hip/hip_runtime.h>
#include <math.h>

#define ALPHA 0.2f
#define NP 50000
#define NA 25000
#define NBINS 150000          // P: 2*NP interleaved bins, then A: 2*NA
#define ABASE 100000          // bin base for A nodes (even -> node bins stay bucket-local)
#define NBUCK 586             // ceil(NBINS/256)
#define CH 4096               // edges per scatter block (= 16*256, static unroll)
#define CAP 8192              // fixed bucket region capacity (max observed ~3.9k)
#define GP ((NP + 63) / 64)   // 782 xform-P blocks
#define GA ((NA + 63) / 64)   // 391 xform-A blocks
#define GATB ((NP + NA) / 4)  // 18750 gat blocks (divides exactly)
#define SNB_P 128
#define SNB_A 64
#define SNB (SNB_P + SNB_A)

typedef unsigned short u16;
typedef __attribute__((ext_vector_type(8))) short bf16x8;
typedef __attribute__((ext_vector_type(8))) unsigned short u16x8;
typedef __attribute__((ext_vector_type(4))) float f32x4;

__device__ __forceinline__ float bf2f(u16 u) { return __uint_as_float(((unsigned)u) << 16); }
__device__ __forceinline__ u16 f2bf(float f) {
    unsigned x = __float_as_uint(f);
    return (u16)((x + 0x7fffu + ((x >> 16) & 1u)) >> 16);   // RNE
}

// =============== args ===============
struct FrontArgs {
    const float *feat_P, *feat_A, *feat_S;
    const float *W_P, *b_P, *W_A, *b_A, *W_p2p, *b_p2p, *W_p2a, *b_p2a,
                *W_a2p, *b_a2p, *W_a2a, *b_a2a, *W_p2s, *b_p2s, *W_a2s, *b_a2s,
                *W_in, *b_in;
    const float *a_p2p, *a_p2a, *a_a2p, *a_a2a, *a_p2s, *a_a2s;
    float *WhP, *WhA;
    u16 *z_p2p, *z_p2a, *z_p2s, *z_a2p, *z_a2a, *z_a2s;
    float *ss_p2p, *sd_p2p, *ss_p2a, *sd_p2a, *ss_a2p, *sd_a2p, *ss_a2a, *sd_a2a,
          *ss_p2s, *ss_a2s;
    float *sdst2, *outS, *den2, *numP, *numA;
    int *done;
    // scatter role:
    const int *src_p2p, *dst_p2p, *src_a2p, *dst_a2p,
              *src_p2a, *dst_p2a, *src_a2a, *dst_a2a;
    int E_p2p, E_a2p, E_p2a, E_a2a, E_tot, nblk;
    int *cursor0, *ebuf;
};

// =============== MFMA 4-matrix transform body (per node type) ===============
__device__ __forceinline__ void xform_body(int bid,
    const float* __restrict__ X, int N,
    const float* __restrict__ W0, const float* __restrict__ b0, float* __restrict__ Wh,
    const float* __restrict__ dA, float* __restrict__ sdA,
    const float* __restrict__ dB, float* __restrict__ sdB,
    const float* __restrict__ W1, const float* __restrict__ b1, u16* __restrict__ z1,
    const float* __restrict__ v1, float* __restrict__ s1,
    const float* __restrict__ W2, const float* __restrict__ b2, u16* __restrict__ z2,
    const float* __restrict__ v2, float* __restrict__ s2,
    const float* __restrict__ W3, const float* __restrict__ b3, u16* __restrict__ z3,
    const float* __restrict__ v3, float* __restrict__ s3)
{
    int tid = threadIdx.x, wv = tid >> 6, lane = tid & 63;
    int g = lane >> 4, li = lane & 15;
    const float* Wm = wv == 0 ? W0 : wv == 1 ? W1 : wv == 2 ? W2 : W3;
    const float* bm = wv == 0 ? b0 : wv == 1 ? b1 : wv == 2 ? b2 : b3;
    const float* dv = wv == 0 ? dA : wv == 1 ? v1 : wv == 2 ? v2 : v3;
    float* sm       = wv == 0 ? sdA : wv == 1 ? s1 : wv == 2 ? s2 : s3;
    u16* zm         = wv == 1 ? z1 : wv == 2 ? z2 : wv == 3 ? z3 : nullptr;

    bf16x8 Bf[4][2];
#pragma unroll
    for (int cb = 0; cb < 4; ++cb)
#pragma unroll
        for (int kc = 0; kc < 2; ++kc) {
            bf16x8 t;
#pragma unroll
            for (int j = 0; j < 8; ++j)
                t[j] = (short)f2bf(Wm[(kc * 32 + g * 8 + j) * 64 + cb * 16 + li]);
            Bf[cb][kc] = t;
        }
    float bl[4], dvl[4], dbl[4];
#pragma unroll
    for (int cb = 0; cb < 4; ++cb) {
        bl[cb]  = bm[cb * 16 + li];
        dvl[cb] = dv[cb * 16 + li];
        dbl[cb] = (wv == 0) ? dB[cb * 16 + li] : 0.f;
    }

    int base0 = bid * 64;
#pragma unroll
    for (int rt = 0; rt < 4; ++rt) {
        int rbase = base0 + rt * 16;
        if (rbase >= N) break;
        int rowC = min(rbase + li, N - 1);
        bf16x8 Af[2];
#pragma unroll
        for (int kc = 0; kc < 2; ++kc) {
            const float* xp = X + (long long)rowC * 64 + kc * 32 + g * 8;
            float4 x0 = *(const float4*)xp;
            float4 x1 = *(const float4*)(xp + 4);
            bf16x8 t;
            t[0] = (short)f2bf(x0.x); t[1] = (short)f2bf(x0.y);
            t[2] = (short)f2bf(x0.z); t[3] = (short)f2bf(x0.w);
            t[4] = (short)f2bf(x1.x); t[5] = (short)f2bf(x1.y);
            t[6] = (short)f2bf(x1.z); t[7] = (short)f2bf(x1.w);
            Af[kc] = t;
        }
        f32x4 acc[4] = {{0,0,0,0},{0,0,0,0},{0,0,0,0},{0,0,0,0}};
#pragma unroll
        for (int kc = 0; kc < 2; ++kc)
#pragma unroll
            for (int cb = 0; cb < 4; ++cb)
                acc[cb] = __builtin_amdgcn_mfma_f32_16x16x32_bf16(Af[kc], Bf[cb][kc], acc[cb], 0, 0, 0);
        float pd[4] = {0,0,0,0}, pb[4] = {0,0,0,0};
#pragma unroll
        for (int cb = 0; cb < 4; ++cb)
#pragma unroll
            for (int r = 0; r < 4; ++r) {
                float val = acc[cb][r] + bl[cb];
                acc[cb][r] = val;
                pd[r] = fmaf(val, dvl[cb], pd[r]);
                pb[r] = fmaf(val, dbl[cb], pb[r]);
            }
#pragma unroll
        for (int o = 1; o < 16; o <<= 1)
#pragma unroll
            for (int r = 0; r < 4; ++r) {
                pd[r] += __shfl_xor(pd[r], o, 64);
                pb[r] += __shfl_xor(pb[r], o, 64);
            }
        int rg = rbase + g * 4;
        if (li == 0) {
#pragma unroll
            for (int r = 0; r < 4; ++r) {
                int row = rg + r;
                if (row < N) {
                    sm[row] = pd[r];
                    if (wv == 0) sdB[row] = pb[r];
                }
            }
        }
        if (wv == 0) {
#pragma unroll
            for (int r = 0; r < 4; ++r) {
                int row = rg + r;
                if (row < N)
#pragma unroll
                    for (int cb = 0; cb < 4; ++cb)
                        Wh[(long long)row * 64 + cb * 16 + li] = acc[cb][r];
            }
        } else {
#pragma unroll
            for (int r = 0; r < 4; ++r) {
                int row = rg + r;
                if (row < N)
#pragma unroll
                    for (int cb = 0; cb < 4; ++cb)
                        zm[(long long)row * 64 + cb * 16 + li] = f2bf(acc[cb][r]);
            }
        }
    }
}

// =============== edge decode ===============
__device__ __forceinline__ void edge_decode(int k,
    const int* __restrict__ s0, const int* __restrict__ d0, int E0,
    const int* __restrict__ s1, const int* __restrict__ d1, int E1,
    const int* __restrict__ s2, const int* __restrict__ d2, int E2,
    const int* __restrict__ s3, const int* __restrict__ d3,
    int& src, int& bin) {
    if (k < E0) { src = s0[k]; bin = 2 * d0[k]; return; }
    k -= E0; if (k < E1) { src = s1[k]; bin = 2 * d1[k] + 1; return; }
    k -= E1; if (k < E2) { src = s2[k]; bin = ABASE + 2 * d2[k]; return; }
    k -= E2; src = s3[k]; bin = ABASE + 2 * d3[k] + 1;
}

// =============== fused front: scatter | xform P | xform A | state_prep ===============
__global__ __launch_bounds__(256) void fused_front(FrontArgs A) {
    __shared__ int h[NBUCK];
    __shared__ int base[NBUCK];
    int bid = blockIdx.x;
    int tid = threadIdx.x;
    if (bid < A.nblk) {
        // ---- scatter role: window reservation into fixed bucket regions ----
        for (int i = tid; i < NBUCK; i += 256) h[i] = 0;
        __syncthreads();
        int b0 = bid * CH;
        int b1 = min(b0 + CH, A.E_tot);
        int cbin[16], csrc[16];
#pragma unroll
        for (int it = 0; it < 16; ++it) {
            int i = b0 + it * 256 + tid;
            int bin = -1, src = 0;
            if (i < b1)
                edge_decode(i, A.src_p2p, A.dst_p2p, A.E_p2p,
                            A.src_a2p, A.dst_a2p, A.E_a2p,
                            A.src_p2a, A.dst_p2a, A.E_p2a,
                            A.src_a2a, A.dst_a2a, src, bin);
            cbin[it] = bin; csrc[it] = src;
            if (bin >= 0) atomicAdd(&h[bin >> 8], 1);
        }
        __syncthreads();
        for (int i = tid; i < NBUCK; i += 256) {
            int c = h[i];
            base[i] = c ? (i * CAP + atomicAdd(&A.cursor0[i], c)) : 0;
            h[i] = 0;                           // reuse as local cursor
        }
        __syncthreads();
#pragma unroll
        for (int it = 0; it < 16; ++it) {
            int bin = cbin[it];
            if (bin >= 0) {
                int bk = bin >> 8;
                int pos = base[bk] + atomicAdd(&h[bk], 1);
                if (pos < (bk + 1) * CAP)       // capacity guard (never hit: max ~3.9k < 8192)
                    A.ebuf[pos] = csrc[it] | ((bin & 255) << 16);
            }
        }
        return;
    }
    bid -= A.nblk;
    if (bid < GP) {
        xform_body(bid, A.feat_P, NP,
                   A.W_P, A.b_P, A.WhP, A.a_p2p + 64, A.sd_p2p, A.a_a2p + 64, A.sd_a2p,
                   A.W_p2p, A.b_p2p, A.z_p2p, A.a_p2p, A.ss_p2p,
                   A.W_p2a, A.b_p2a, A.z_p2a, A.a_p2a, A.ss_p2a,
                   A.W_p2s, A.b_p2s, A.z_p2s, A.a_p2s, A.ss_p2s);
        return;
    }
    bid -= GP;
    if (bid < GA) {
        xform_body(bid, A.feat_A, NA,
                   A.W_A, A.b_A, A.WhA, A.a_p2a + 64, A.sd_p2a, A.a_a2a + 64, A.sd_a2a,
                   A.W_a2p, A.b_a2p, A.z_a2p, A.a_a2p, A.ss_a2p,
                   A.W_a2a, A.b_a2a, A.z_a2a, A.a_a2a, A.ss_a2a,
                   A.W_a2s, A.b_a2s, A.z_a2s, A.a_a2s, A.ss_a2s);
        return;
    }
    // ---- state_prep role (last block) + zero den/num/done ----
    if (tid < 64) {
        int c = tid;
        float acc = A.b_in[c];
        for (int k = 0; k < 64; ++k) acc = fmaf(A.feat_S[k], A.W_in[k * 64 + c], acc);
        A.outS[c] = acc;                       // Wh_in staged in outS
        float v0 = acc * A.a_p2s[64 + c];
        float v1 = acc * A.a_a2s[64 + c];
#pragma unroll
        for (int off = 32; off > 0; off >>= 1) {
            v0 += __shfl_down(v0, off, 64);
            v1 += __shfl_down(v1, off, 64);
        }
        if (c == 0) { A.sdst2[0] = v0; A.sdst2[1] = v1; }
    } else if (tid < 128) A.numP[tid - 64] = 0.f;
    else if (tid < 192)   A.numA[tid - 128] = 0.f;
    else if (tid == 192)  A.den2[0] = 0.f;
    else if (tid == 193)  A.den2[1] = 0.f;
    else if (tid == 194)  *A.done = 0;
}

// =============== fine sort: bucket region -> bin-sorted ssrc + offs (257/bucket) ===============
__global__ __launch_bounds__(256) void fine_sort(
    const int* __restrict__ ebuf, const int* __restrict__ cursor0,
    int* __restrict__ ssrc, int* __restrict__ offs) {
    __shared__ int lsrc[CAP];
    __shared__ int lcnt[256];
    __shared__ int loff[256];
    __shared__ int lcur[256];
    __shared__ int wtot[4];
    int b = blockIdx.x;
    int tid = threadIdx.x, lane = tid & 63, wv = tid >> 6;
    int bstart = b * CAP;
    int cnt = min(cursor0[b], CAP);
    int bend = bstart + cnt;
    lcnt[tid] = 0;
    __syncthreads();
    for (int e = bstart + tid; e < bend; e += 256)
        atomicAdd(&lcnt[((unsigned)ebuf[e]) >> 16], 1);
    __syncthreads();
    int v = lcnt[tid];
    int x = v;
#pragma unroll
    for (int o = 1; o < 64; o <<= 1) {
        int y = __shfl_up(x, o, 64);
        if (lane >= o) x += y;
    }
    if (lane == 63) wtot[wv] = x;
    __syncthreads();
    int woff = 0;
    for (int j = 0; j < wv; ++j) woff += wtot[j];
    int excl = x + woff - v;
    loff[tid] = excl;
    lcur[tid] = excl;
    __syncthreads();
    for (int e = bstart + tid; e < bend; e += 256) {
        int val = ebuf[e];
        int pos = atomicAdd(&lcur[((unsigned)val) >> 16], 1);
        lsrc[pos] = val & 0xFFFF;
    }
    __syncthreads();
    for (int i = tid; i < cnt; i += 256) ssrc[bstart + i] = lsrc[i];   // coalesced
    offs[b * 257 + tid] = bstart + loff[tid];
    if (tid == 0) offs[b * 257 + 256] = bend;
}

// =============== per-segment gather, 8 edges in flight (R8-proven structure) ===============
__device__ __forceinline__ void seg_gat_g8(const int* __restrict__ ssrc, int s0, int s1,
                                           const float* __restrict__ ss, float sd,
                                           const u16* __restrict__ z, int lane,
                                           float* __restrict__ acc) {
    int cnt = s1 - s0;
    if (cnt <= 0) return;
    int egrp = lane >> 3, cg8 = (lane & 7) * 8;
    if (cnt <= 64) {                    // fast path (deg <= 64: essentially always)
        int s = 0; float w = 0.f;
        if (lane < cnt) {
            s = ssrc[s0 + lane];        // coalesced
            float e = ss[s] + sd;
            e = e > 0.f ? e : ALPHA * e;
            w = __expf(e);
        }
        float den = w;
#pragma unroll
        for (int o = 32; o > 0; o >>= 1) den += __shfl_xor(den, o, 64);
        w *= 1.f / den;
        int nit = (cnt + 7) >> 3;
        for (int it = 0; it < nit; ++it) {
            int ei = it * 8 + egrp;
            float wt = __shfl(w, ei, 64);   // 0 for ei >= cnt
            int   st = __shfl(s, ei, 64);
            u16x8 q = *(const u16x8*)(z + (long long)st * 64 + cg8);
#pragma unroll
            for (int j = 0; j < 8; ++j)
                acc[j] = fmaf(wt, bf2f(q[j]), acc[j]);
        }
    } else {                            // general path (rare)
        float den = 0.f;
        for (int i = s0 + lane; i < s1; i += 64) {
            float e = ss[ssrc[i]] + sd; e = e > 0.f ? e : ALPHA * e; den += __expf(e);
        }
#pragma unroll
        for (int o = 32; o > 0; o >>= 1) den += __shfl_xor(den, o, 64);
        float inv = 1.f / den;
        for (int c = s0; c < s1; c += 64) {
            int i = c + lane; int s = 0; float w = 0.f;
            if (i < s1) {
                s = ssrc[i];
                float e = ss[s] + sd; e = e > 0.f ? e : ALPHA * e;
                w = __expf(e) * inv;
            }
            int cc = min(64, s1 - c);
            int nit = (cc + 7) >> 3;
            for (int it = 0; it < nit; ++it) {
                int ei = it * 8 + egrp;
                float wt = __shfl(w, ei, 64);
                int   st = __shfl(s, ei, 64);
                u16x8 q = *(const u16x8*)(z + (long long)st * 64 + cg8);
#pragma unroll
                for (int j = 0; j < 8; ++j)
                    acc[j] = fmaf(wt, bf2f(q[j]), acc[j]);
            }
        }
    }
}

// =============== fused back: state_all FIRST | gat (per-segment) ===============
__global__ __launch_bounds__(256) void fused_back(
    const int* __restrict__ ssrc, const int* __restrict__ offs,
    const float* __restrict__ WhP, float* __restrict__ outP,
    const float* __restrict__ WhA, float* __restrict__ outA,
    const float* __restrict__ ss_p2p, const float* __restrict__ sd_p2p, const u16* __restrict__ z_p2p,
    const float* __restrict__ ss_a2p, const float* __restrict__ sd_a2p, const u16* __restrict__ z_a2p,
    const float* __restrict__ ss_p2a, const float* __restrict__ sd_p2a, const u16* __restrict__ z_p2a,
    const float* __restrict__ ss_a2a, const float* __restrict__ sd_a2a, const u16* __restrict__ z_a2a,
    const int* __restrict__ srcP, const float* __restrict__ ssP, const u16* __restrict__ zP, int EP,
    const int* __restrict__ srcA, const float* __restrict__ ssA, const u16* __restrict__ zA, int EA,
    const float* __restrict__ sdst2, float* __restrict__ numP, float* __restrict__ numA,
    float* __restrict__ den2, int* __restrict__ done, float* __restrict__ outS) {
    int tid = threadIdx.x, lane = tid & 63, wv = tid >> 6;
    if ((int)blockIdx.x >= SNB) {
        // ---- gat role: wave per node, per-segment fast path (R8 structure) ----
        int g = ((int)blockIdx.x - SNB) * 4 + wv;
        bool isP = g < NP;
        int d = isP ? g : g - NP;
        int bin0 = isP ? 2 * d : ABASE + 2 * d;
        int obase = (bin0 >> 8) * 257 + (bin0 & 255);
        int e0 = offs[obase], e1 = offs[obase + 1], e2 = offs[obase + 2];
        const float* ss0 = isP ? ss_p2p : ss_p2a;
        const float* ss1 = isP ? ss_a2p : ss_a2a;
        const u16* z0 = isP ? z_p2p : z_p2a;
        const u16* z1 = isP ? z_a2p : z_a2a;
        float sd0v = (isP ? sd_p2p : sd_p2a)[d];
        float sd1v = (isP ? sd_a2p : sd_a2a)[d];
        float acc[8] = {0.f, 0.f, 0.f, 0.f, 0.f, 0.f, 0.f, 0.f};
        seg_gat_g8(ssrc, e0, e1, ss0, sd0v, z0, lane, acc);
        seg_gat_g8(ssrc, e1, e2, ss1, sd1v, z1, lane, acc);
#pragma unroll
        for (int o = 8; o <= 32; o <<= 1)
#pragma unroll
            for (int j = 0; j < 8; ++j)
                acc[j] += __shfl_xor(acc[j], o, 64);
        if (lane < 8) {
            const float* Wh = isP ? WhP : WhA;
            float* outp = isP ? outP : outA;
            const float* sp = &Wh[(long long)d * 64 + lane * 8];
            float4 s0v = *(const float4*)sp;
            float4 s1v = *(const float4*)(sp + 4);
            float4 r0, r1;
            r0.x = fmaxf(s0v.x + acc[0], 0.f); r0.y = fmaxf(s0v.y + acc[1], 0.f);
            r0.z = fmaxf(s0v.z + acc[2], 0.f); r0.w = fmaxf(s0v.w + acc[3], 0.f);
            r1.x = fmaxf(s1v.x + acc[4], 0.f); r1.y = fmaxf(s1v.y + acc[5], 0.f);
            r1.z = fmaxf(s1v.z + acc[6], 0.f); r1.w = fmaxf(s1v.w + acc[7], 0.f);
            float* op = &outp[(long long)d * 64 + lane * 8];
            *(float4*)op = r0;
            *(float4*)(op + 4) = r1;
        }
        return;
    }
    // ---- state role (blocks 0..SNB-1: launched FIRST, overlaps gat fill) ----
    __shared__ float red[4][64];
    __shared__ float dred[4];
    __shared__ int tick;
    int sb = blockIdx.x;
    bool isP = sb < SNB_P;
    const int* src = isP ? srcP : srcA;
    const float* ss = isP ? ssP : ssA;
    const u16* z = isP ? zP : zA;
    int E = isP ? EP : EA;
    float sdst = sdst2[isP ? 0 : 1];
    float* num = isP ? numP : numA;
    int bidl = isP ? sb : sb - SNB_P;
    int nb = isP ? SNB_P : SNB_A;
    int egrp = lane >> 3, cg8 = (lane & 7) * 8;
    int gw = bidl * 4 + wv;
    int waves = nb * 4;
    float acc[8] = {0,0,0,0,0,0,0,0};
    float dpart = 0.f;
    for (int base = gw * 8; base < E; base += waves * 8) {
        int i = base + egrp;
        float w = 0.f; int ri = 0;
        if (i < E) {
            ri = src[i];
            float e = ss[ri] + sdst;
            e = e > 0.f ? e : ALPHA * e;
            w = __expf(e);
        }
        dpart += w;                            // each edge counted by 8 lanes -> /8 later
        u16x8 q = *(const u16x8*)(z + (long long)ri * 64 + cg8);
#pragma unroll
        for (int j = 0; j < 8; ++j)
            acc[j] = fmaf(w, bf2f(q[j]), acc[j]);
    }
#pragma unroll
    for (int o = 8; o <= 32; o <<= 1)
#pragma unroll
        for (int j = 0; j < 8; ++j)
            acc[j] += __shfl_xor(acc[j], o, 64);
#pragma unroll
    for (int o = 32; o > 0; o >>= 1) dpart += __shfl_xor(dpart, o, 64);
    if (lane < 8)
#pragma unroll
        for (int j = 0; j < 8; ++j) red[wv][lane * 8 + j] = acc[j];
    if (lane == 0) dred[wv] = dpart;
    __syncthreads();
    if (tid < 64) {
        float t = red[0][tid] + red[1][tid] + red[2][tid] + red[3][tid];
        atomicAdd(&num[tid], t);
    }
    if (tid == 64) {
        float dtot = (dred[0] + dred[1] + dred[2] + dred[3]) * 0.125f;
        atomicAdd(&den2[isP ? 0 : 1], dtot);
    }
    __threadfence();
    __syncthreads();
    if (tid == 0) tick = atomicAdd(done, 1);
    __syncthreads();
    if (tick == SNB - 1 && tid < 64) {         // last state block finalizes
        float dP = __hip_atomic_load(&den2[0], __ATOMIC_ACQUIRE, __HIP_MEMORY_SCOPE_AGENT);
        float dA = __hip_atomic_load(&den2[1], __ATOMIC_ACQUIRE, __HIP_MEMORY_SCOPE_AGENT);
        float nP = __hip_atomic_load(&numP[tid], __ATOMIC_ACQUIRE, __HIP_MEMORY_SCOPE_AGENT);
        float nA = __hip_atomic_load(&numA[tid], __ATOMIC_ACQUIRE, __HIP_MEMORY_SCOPE_AGENT);
        float whin = outS[tid];
        outS[tid] = fmaxf(whin + nP / dP + nA / dA, 0.f);
    }
}

extern "C" void kernel_launch(void* const* d_in, const int* in_sizes, int n_in,
                              void* d_out, int out_size, void* d_ws, size_t ws_size,
                              hipStream_t stream) {
    const float* feat_P = (const float*)d_in[0];
    const float* feat_A = (const float*)d_in[1];
    const float* feat_S = (const float*)d_in[2];
    const float* W_P   = (const float*)d_in[3];  const float* b_P   = (const float*)d_in[4];
    const float* W_A   = (const float*)d_in[5];  const float* b_A   = (const float*)d_in[6];
    const float* W_p2p = (const float*)d_in[7];  const float* b_p2p = (const float*)d_in[8];
    const float* W_p2a = (const float*)d_in[9];  const float* b_p2a = (const float*)d_in[10];
    const float* W_a2p = (const float*)d_in[11]; const float* b_a2p = (const float*)d_in[12];
    const float* W_a2a = (const float*)d_in[13]; const float* b_a2a = (const float*)d_in[14];
    const float* W_p2s = (const float*)d_in[15]; const float* b_p2s = (const float*)d_in[16];
    const float* W_a2s = (const float*)d_in[17]; const float* b_a2s = (const float*)d_in[18];
    const float* W_in  = (const float*)d_in[19]; const float* b_in  = (const float*)d_in[20];
    const float* a_p2p = (const float*)d_in[21];
    const float* a_p2a = (const float*)d_in[22];
    const float* a_a2p = (const float*)d_in[23];
    const float* a_a2a = (const float*)d_in[24];
    const float* a_p2s = (const float*)d_in[25];
    const float* a_a2s = (const float*)d_in[26];
    const int* src_p2p = (const int*)d_in[27]; const int* dst_p2p = (const int*)d_in[28];
    const int* src_p2a = (const int*)d_in[29]; const int* dst_p2a = (const int*)d_in[30];
    const int* src_a2p = (const int*)d_in[31]; const int* dst_a2p = (const int*)d_in[32];
    const int* src_a2a = (const int*)d_in[33]; const int* dst_a2a = (const int*)d_in[34];
    const int* src_p2s = (const int*)d_in[35];
    const int* src_a2s = (const int*)d_in[37];
    int E_p2p = in_sizes[27], E_p2a = in_sizes[29], E_a2p = in_sizes[31], E_a2a = in_sizes[33];
    int E_p2s = in_sizes[35], E_a2s = in_sizes[37];
    int E_tot = E_p2p + E_a2p + E_p2a + E_a2a;

    float* out = (float*)d_out;
    float* outP = out;
    float* outA = out + (long long)NP * 64;
    float* outS = out + (long long)(NP + NA) * 64;

    // ---- workspace layout ----
    float* ws = (float*)d_ws;
    float* WhP = ws; ws += (long long)NP * 64;
    float* WhA = ws; ws += (long long)NA * 64;
    u16* z_p2p = (u16*)ws; ws += (long long)NP * 32;
    u16* z_p2a = (u16*)ws; ws += (long long)NP * 32;
    u16* z_p2s = (u16*)ws; ws += (long long)NP * 32;
    u16* z_a2p = (u16*)ws; ws += (long long)NA * 32;
    u16* z_a2a = (u16*)ws; ws += (long long)NA * 32;
    u16* z_a2s = (u16*)ws; ws += (long long)NA * 32;
    float* ss_p2p = ws; ws += NP;  float* sd_p2p = ws; ws += NP;
    float* ss_p2a = ws; ws += NP;  float* sd_p2a = ws; ws += NA;
    float* ss_a2p = ws; ws += NA;  float* sd_a2p = ws; ws += NP;
    float* ss_a2a = ws; ws += NA;  float* sd_a2a = ws; ws += NA;
    float* ss_p2s = ws; ws += NP;
    float* ss_a2s = ws; ws += NA;
    float* sdst2  = ws; ws += 2;
    float* den2   = ws; ws += 2;
    float* numP   = ws; ws += 64;
    float* numA   = ws; ws += 64;
    int*   done   = (int*)ws; ws += 1;
    // ---- zeroed-every-call region (tiny memset) ----
    int* cursor0 = (int*)ws; ws += NBUCK;
    // ---- rest ----
    int* iw = (int*)ws;
    int* ebuf = iw; iw += NBUCK * CAP;
    int* ssrc = iw; iw += NBUCK * CAP;
    int* offs = iw; iw += NBUCK * 257 + 1;

    const int T = 256;
    int nblk = (E_tot + CH - 1) / CH;

    hipMemsetAsync(cursor0, 0, (size_t)NBUCK * 4, stream);

    // ---- fused front: scatter | xform P | xform A | state_prep ----
    FrontArgs FA;
    FA.feat_P = feat_P; FA.feat_A = feat_A; FA.feat_S = feat_S;
    FA.W_P = W_P; FA.b_P = b_P; FA.W_A = W_A; FA.b_A = b_A;
    FA.W_p2p = W_p2p; FA.b_p2p = b_p2p; FA.W_p2a = W_p2a; FA.b_p2a = b_p2a;
    FA.W_a2p = W_a2p; FA.b_a2p = b_a2p; FA.W_a2a = W_a2a; FA.b_a2a = b_a2a;
    FA.W_p2s = W_p2s; FA.b_p2s = b_p2s; FA.W_a2s = W_a2s; FA.b_a2s = b_a2s;
    FA.W_in = W_in; FA.b_in = b_in;
    FA.a_p2p = a_p2p; FA.a_p2a = a_p2a; FA.a_a2p = a_a2p; FA.a_a2a = a_a2a;
    FA.a_p2s = a_p2s; FA.a_a2s = a_a2s;
    FA.WhP = WhP; FA.WhA = WhA;
    FA.z_p2p = z_p2p; FA.z_p2a = z_p2a; FA.z_p2s = z_p2s;
    FA.z_a2p = z_a2p; FA.z_a2a = z_a2a; FA.z_a2s = z_a2s;
    FA.ss_p2p = ss_p2p; FA.sd_p2p = sd_p2p; FA.ss_p2a = ss_p2a; FA.sd_p2a = sd_p2a;
    FA.ss_a2p = ss_a2p; FA.sd_a2p = sd_a2p; FA.ss_a2a = ss_a2a; FA.sd_a2a = sd_a2a;
    FA.ss_p2s = ss_p2s; FA.ss_a2s = ss_a2s;
    FA.sdst2 = sdst2; FA.outS = outS; FA.den2 = den2; FA.numP = numP; FA.numA = numA;
    FA.done = done;
    FA.src_p2p = src_p2p; FA.dst_p2p = dst_p2p; FA.src_a2p = src_a2p; FA.dst_a2p = dst_a2p;
    FA.src_p2a = src_p2a; FA.dst_p2a = dst_p2a; FA.src_a2a = src_a2a; FA.dst_a2a = dst_a2a;
    FA.E_p2p = E_p2p; FA.E_a2p = E_a2p; FA.E_p2a = E_p2a; FA.E_a2a = E_a2a;
    FA.E_tot = E_tot; FA.nblk = nblk;
    FA.cursor0 = cursor0; FA.ebuf = ebuf;
    fused_front<<<nblk + GP + GA + 1, T, 0, stream>>>(FA);

    // ---- fine sort ----
    fine_sort<<<NBUCK, T, 0, stream>>>(ebuf, cursor0, ssrc, offs);

    // ---- fused back: state_all (first) | gat (per-segment) ----
    fused_back<<<SNB + GATB, T, 0, stream>>>(ssrc, offs,
        WhP, outP, WhA, outA,
        ss_p2p, sd_p2p, z_p2p, ss_a2p, sd_a2p, z_a2p,
        ss_p2a, sd_p2a, z_p2a, ss_a2a, sd_a2a, z_a2a,
        src_p2s, ss_p2s, z_p2s, E_p2s,
        src_a2s, ss_a2s, z_a2s, E_a2s,
        sdst2, numP, numA, den2, done, outS);
}